// Round 2
// baseline (1147.488 us; speedup 1.0000x reference)
//
#include <hip/hip_runtime.h>
#include <stdint.h>

#define NN 8192
#define MM 16
#define FN 128
#define HH 512
#define NBLK 512

typedef unsigned short u16;
typedef unsigned int u32;
typedef __bf16 bf16;
typedef __bf16 bf16x8 __attribute__((ext_vector_type(8)));
typedef float f32x4 __attribute__((ext_vector_type(4)));

// async global->LDS, 16B/lane; LDS dest = wave-uniform base + lane*16
__device__ __forceinline__ void gld_lds16(const u16* g, u16* l) {
  __builtin_amdgcn_global_load_lds(
      (const __attribute__((address_space(1))) void*)g,
      (__attribute__((address_space(3))) void*)l, 16, 0, 0);
}

// ---- software grid barrier: monotonic agent-scope counter, no reset ----
// All NBLK blocks are co-resident (__launch_bounds__(256,2): <=256 VGPR,
// 24KB LDS -> 2 blocks/CU x 256 CU = 512). __threadfence() both sides
// gives agent-scope release/acquire (L2 writeback + L1/L2 invalidate),
// covering plain loads AND the global_load_lds DMA path across XCDs.
__device__ __forceinline__ void grid_bar(u32* bar, u32 target) {
  __threadfence();  // release: my writes visible agent-wide
  __syncthreads();
  if (threadIdx.x == 0) {
    __hip_atomic_fetch_add(bar, 1u, __ATOMIC_ACQ_REL, __HIP_MEMORY_SCOPE_AGENT);
    while (__hip_atomic_load(bar, __ATOMIC_ACQUIRE, __HIP_MEMORY_SCOPE_AGENT) <
           target)
      __builtin_amdgcn_s_sleep(2);
  }
  __syncthreads();
  __threadfence();  // acquire: drop stale cached lines for all threads
}

// ---- dtype probes (per-wave; ~2 cached loads + ballot) ----
__device__ __forceinline__ int probe_f32(const u16* w) {
  int lane = threadIdx.x & 63;
  int e = (w[2 * lane] >> 7) & 0xFF;
  unsigned long long m = __ballot(!(e == 0 || (e >= 90 && e <= 140)));
  return __popcll(m) >= 8;
}
__device__ __forceinline__ int probe_i64(const u32* w) {
  int lane = threadIdx.x & 63;
  unsigned long long m = __ballot(lane < 32 && w[2 * lane + 1] != 0);
  return m == 0;
}

__device__ __forceinline__ bf16 cvt_elem(const void* p, size_t i, int f32) {
  return f32 ? (bf16)((const float*)p)[i] : ((const bf16*)p)[i];
}

// ---- transpose one 32x32 tile of W (512 x 512) -> T (512 x 512) ----
__device__ __forceinline__ void transpose_tile(const void* __restrict__ W,
                                               u16* __restrict__ T, int tt,
                                               int f32in, u16* sm) {
  const int k0 = (tt >> 4) * 32, n0 = (tt & 15) * 32;
  const int tx = threadIdx.x & 31, ty = threadIdx.x >> 5;  // ty 0..7
#pragma unroll
  for (int r = ty; r < 32; r += 8) {
    bf16 v = cvt_elem(W, (size_t)(k0 + r) * HH + n0 + tx, f32in);
    sm[r * 33 + tx] = *(u16*)&v;
  }
  __syncthreads();
#pragma unroll
  for (int r = ty; r < 32; r += 8)
    T[(size_t)(n0 + r) * HH + k0 + tx] = sm[tx * 33 + r];
}

// ---- GEMM tile: C[rtile*64..+64][ctile*128..+128] = A @ Bt^T (+ biasf)
// 256 thr / 4 waves (2x2), wave 32x64 (2x4 accs of 16x16x32), BK=64,
// gld_lds + XOR swizzle (LDS chunk (row,cc) holds k-chunk gc = cc^(row&7)).
// R5-R8-verified: correct, 0 bank conflicts. Writes bf16, row stride cstride.
__device__ __forceinline__ void gemm_tile(const void* __restrict__ A, int K,
                                          int af32, const u16* __restrict__ Bt,
                                          const float* __restrict__ biasf,
                                          int rtile, int ctile,
                                          u16* __restrict__ C, int cstride,
                                          u16* As, u16* Bs) {
  const int tid = threadIdx.x;
  const int wave = tid >> 6, lane = tid & 63;
  const int wr = wave >> 1, wc = wave & 1;
  const int quad = lane >> 4, l16 = lane & 15;
  f32x4 acc[2][4] = {};

  int arow[2], agc[2], brow[4], bgc[4];
#pragma unroll
  for (int i = 0; i < 2; ++i) {
    int c = i * 256 + tid;
    arow[i] = c >> 3;
    agc[i] = (c & 7) ^ (arow[i] & 7);
  }
#pragma unroll
  for (int i = 0; i < 4; ++i) {
    int c = i * 256 + tid;
    brow[i] = c >> 3;
    bgc[i] = (c & 7) ^ (brow[i] & 7);
  }
  u16* AsW = As + wave * 512;  // wave-uniform LDS bases (chunk c -> c*16 B)
  u16* BsW = Bs + wave * 512;

  for (int k0 = 0; k0 < K; k0 += 64) {
    __syncthreads();  // prev iter's ds_reads done
    if (af32) {
      const float* Af = (const float*)A;
      bf16x8 v[2];
#pragma unroll
      for (int i = 0; i < 2; ++i) {
        const float* p = &Af[(size_t)(rtile * 64 + arow[i]) * K + k0 + agc[i] * 8];
        f32x4 x0 = *(const f32x4*)p, x1 = *(const f32x4*)(p + 4);
#pragma unroll
        for (int t = 0; t < 4; ++t) {
          v[i][t] = (bf16)x0[t];
          v[i][4 + t] = (bf16)x1[t];
        }
      }
#pragma unroll
      for (int i = 0; i < 2; ++i) *(bf16x8*)&As[(i * 256 + tid) * 8] = v[i];
    } else {
      const u16* Ab = (const u16*)A;
#pragma unroll
      for (int i = 0; i < 2; ++i)
        gld_lds16(&Ab[(size_t)(rtile * 64 + arow[i]) * K + k0 + agc[i] * 8],
                  AsW + i * 2048);
    }
#pragma unroll
    for (int i = 0; i < 4; ++i)
      gld_lds16(&Bt[(size_t)(ctile * 128 + brow[i]) * K + k0 + bgc[i] * 8],
                BsW + i * 2048);
    __syncthreads();  // drains vmcnt (DMA complete)
#pragma unroll
    for (int h = 0; h < 2; ++h) {
      bf16x8 af[2], bfr[4];
#pragma unroll
      for (int i = 0; i < 2; ++i) {
        int r = wr * 32 + i * 16 + l16;
        int cc = (h * 4 + quad) ^ (r & 7);
        af[i] = *(const bf16x8*)&As[r * 64 + cc * 8];
      }
#pragma unroll
      for (int j = 0; j < 4; ++j) {
        int n = wc * 64 + j * 16 + l16;
        int cc = (h * 4 + quad) ^ (n & 7);
        bfr[j] = *(const bf16x8*)&Bs[n * 64 + cc * 8];
      }
#pragma unroll
      for (int i = 0; i < 2; ++i)
#pragma unroll
        for (int j = 0; j < 4; ++j)
          acc[i][j] = __builtin_amdgcn_mfma_f32_16x16x32_bf16(af[i], bfr[j],
                                                              acc[i][j], 0, 0, 0);
    }
  }

  // C/D layout: col = lane&15, row = quad*4 + reg (m89/m91)
  const int crow0 = rtile * 64 + wr * 32 + quad * 4;
  const int ccol0 = ctile * 128 + wc * 64 + l16;
#pragma unroll
  for (int j = 0; j < 4; ++j) {
    const int col = ccol0 + j * 16;
    const float bv = biasf ? biasf[col] : 0.f;
#pragma unroll
    for (int i = 0; i < 2; ++i)
#pragma unroll
      for (int r = 0; r < 4; ++r) {
        bf16 o = (bf16)(acc[i][j][r] + bv);
        C[(size_t)(crow0 + i * 16 + r) * cstride + col] = *(u16*)&o;
      }
  }
}

// ---- one agg unit: y[i,:] = act( d[i]*( d[i]*t[i,:] + sum d[j]*t[j,:] ) + b )
// XCD-pinned column strips (R7): strip s read only by blocks with b%8 in
// {2s,2s+1} -> 2 MB of t resident per XCD-pair L2.
template <bool RELU, bool FINAL>
__device__ __forceinline__ void agg_unit(int b, const u16* __restrict__ t,
                                         const int* __restrict__ idx, int i64,
                                         const float* __restrict__ dis,
                                         const void* __restrict__ bias,
                                         int f32io, void* __restrict__ y) {
  const int strip = (b & 7) >> 1;          // 0..3, pinned to XCD pair
  const int grp = (b >> 3) * 2 + (b & 1);  // 0..511 node group
  const int wave = threadIdx.x >> 6, lane = threadIdx.x & 63;
  const int node = grp * 16 + wave * 4 + (lane >> 4);
  const int c0 = strip * 128 + (lane & 15) * 8;
  const float wi = dis[node];
  float acc[8];
  bf16x8 xs = *(const bf16x8*)&t[(size_t)node * HH + c0];
#pragma unroll
  for (int k = 0; k < 8; ++k) acc[k] = wi * wi * (float)xs[k];
#pragma unroll
  for (int e = 0; e < MM; ++e) {
    const int j = idx[(node * MM + e) << i64];
    if (j >= 0) {
      const float w = wi * dis[j];
      bf16x8 v = *(const bf16x8*)&t[(size_t)j * HH + c0];
#pragma unroll
      for (int k = 0; k < 8; ++k) acc[k] += w * (float)v[k];
    }
  }
  float bv[8];
  if (f32io) {
    f32x4 b0 = *(const f32x4*)&((const float*)bias)[c0];
    f32x4 b1 = *(const f32x4*)&((const float*)bias)[c0 + 4];
#pragma unroll
    for (int k = 0; k < 4; ++k) { bv[k] = b0[k]; bv[4 + k] = b1[k]; }
  } else {
    bf16x8 bb = *(const bf16x8*)&((const u16*)bias)[c0];
#pragma unroll
    for (int k = 0; k < 8; ++k) bv[k] = (float)bb[k];
  }
#pragma unroll
  for (int k = 0; k < 8; ++k) {
    acc[k] += bv[k];
    if (RELU) acc[k] = fmaxf(acc[k], 0.f);
  }
  if (FINAL && f32io) {
    float* O = (float*)y;
    f32x4 o0, o1;
#pragma unroll
    for (int k = 0; k < 4; ++k) { o0[k] = acc[k]; o1[k] = acc[4 + k]; }
    *(f32x4*)&O[(size_t)node * HH + c0] = o0;
    *(f32x4*)&O[(size_t)node * HH + c0 + 4] = o1;
  } else {
    bf16x8 o;
#pragma unroll
    for (int k = 0; k < 8; ++k) o[k] = (bf16)acc[k];
    *(bf16x8*)&((u16*)y)[(size_t)node * HH + c0] = o;
  }
}

// ---- single persistent kernel: the whole pipeline, 7 software grid syncs --
// 512 blocks x 256 thr; 24KB LDS + VGPR<=256 ((256,2)) => 2 blocks/CU,
// all 512 co-resident.
__global__ __launch_bounds__(256, 2) void mega_kernel(
    const u16* __restrict__ node, const u32* __restrict__ idxw,
    const void* __restrict__ Wemb, const void* __restrict__ bemb,
    const void* __restrict__ W1, const void* __restrict__ b1,
    const void* __restrict__ W2, const void* __restrict__ b2,
    const void* __restrict__ W3, const void* __restrict__ b3,
    float* __restrict__ dis, float* __restrict__ bvec, u16* __restrict__ TWc,
    u16* __restrict__ WembB, u16* __restrict__ TW1, u16* __restrict__ TW2,
    u16* __restrict__ TW3, u16* __restrict__ xA, u32* __restrict__ bar,
    void* __restrict__ outp) {
  __shared__ __align__(16) u16 As[64 * 64];
  __shared__ __align__(16) u16 Bs[128 * 64];
  const int bid = blockIdx.x, tid = threadIdx.x;
  const int f32in = probe_f32(node);
  const int i64 = probe_i64(idxw);
  const int* idx = (const int*)idxw;
  u16* xO = (u16*)outp;  // d_out doubles as bf16 ping buffer

  // ---- P1: TW1/TW2/TW3 transposes (units 0..767) + WembB copy (768..799)
  for (int u = bid; u < 800; u += NBLK) {
    if (u < 768) {
      const int q = u >> 8, tt = u & 255;
      transpose_tile(q == 0 ? W1 : q == 1 ? W2 : W3,
                     q == 0 ? TW1 : q == 1 ? TW2 : TW3, tt, f32in, As);
      __syncthreads();  // sm (=As) reuse guard across loop iters
    } else {
      const size_t g = ((size_t)(u - 768) * 256 + tid) * 8;  // 8 elems/thread
      bf16x8 o;
      if (f32in) {
        f32x4 a = *(const f32x4*)&((const float*)Wemb)[g];
        f32x4 bq = *(const f32x4*)&((const float*)Wemb)[g + 4];
#pragma unroll
        for (int t = 0; t < 4; ++t) { o[t] = (bf16)a[t]; o[4 + t] = (bf16)bq[t]; }
      } else {
        o = *(const bf16x8*)&((const u16*)Wemb)[g];
      }
      *(bf16x8*)&WembB[g] = o;
    }
  }
  grid_bar(bar, 1 * NBLK);

  // ---- P2: TWc = TW1 @ Wemb^T (blocks 0..7) + bvec (8..9) + deg (10..41)
  if (bid < 8) {
    const u16* Bt = f32in ? WembB : (const u16*)Wemb;
    gemm_tile(TW1, HH, 0, Bt, nullptr, bid, 0, TWc, FN, As, Bs);
  } else if (bid < 10) {
    float* bembS = (float*)Bs;
    bembS[tid] = (float)cvt_elem(bemb, tid, f32in);
    bembS[256 + tid] = (float)cvt_elem(bemb, 256 + tid, f32in);
    __syncthreads();
    const int n = (bid - 8) * 256 + tid;  // 0..511
    float acc = 0.f;
#pragma unroll 8
    for (int m = 0; m < HH; m += 8) {
      bf16x8 w = *(const bf16x8*)&TW1[(size_t)n * HH + m];
#pragma unroll
      for (int jj = 0; jj < 8; ++jj) acc += bembS[m + jj] * (float)w[jj];
    }
    bvec[n] = acc;
  } else if (bid < 42) {
    const int i = (bid - 10) * 256 + tid;
    int c = 1;
#pragma unroll
    for (int e = 0; e < MM; ++e) c += (idx[(i * MM + e) << i64] >= 0) ? 1 : 0;
    dis[i] = rsqrtf((float)c);
  }
  grid_bar(bar, 2 * NBLK);

  // ---- P3: g1: xA = node @ TWc^T + bvec  (K=128, A maybe fp32)
  gemm_tile(node, FN, f32in, TWc, bvec, bid & 127, bid >> 7, xA, HH, As, Bs);
  grid_bar(bar, 3 * NBLK);

  // ---- P4: agg1 + relu  (u = bid+512r keeps u&7 const -> strip pinning)
#pragma unroll
  for (int r = 0; r < 4; ++r)
    agg_unit<true, false>(bid + NBLK * r, xA, idx, i64, dis, b1, f32in, xO);
  grid_bar(bar, 4 * NBLK);

  // ---- P5: gemm2: xA = xO @ TW2^T
  gemm_tile(xO, HH, 0, TW2, nullptr, bid & 127, bid >> 7, xA, HH, As, Bs);
  grid_bar(bar, 5 * NBLK);

  // ---- P6: agg2 + relu
#pragma unroll
  for (int r = 0; r < 4; ++r)
    agg_unit<true, false>(bid + NBLK * r, xA, idx, i64, dis, b2, f32in, xO);
  grid_bar(bar, 6 * NBLK);

  // ---- P7: gemm3: xA = xO @ TW3^T
  gemm_tile(xO, HH, 0, TW3, nullptr, bid & 127, bid >> 7, xA, HH, As, Bs);
  grid_bar(bar, 7 * NBLK);

  // ---- P8: agg3 (no relu, final dtype-matched store to d_out)
#pragma unroll
  for (int r = 0; r < 4; ++r)
    agg_unit<false, true>(bid + NBLK * r, xA, idx, i64, dis, b3, f32in, outp);
}

extern "C" void kernel_launch(void* const* d_in, const int* in_sizes, int n_in,
                              void* d_out, int out_size, void* d_ws, size_t ws_size,
                              hipStream_t stream) {
  const u16* node = (const u16*)d_in[0];
  const u32* idxw = (const u32*)d_in[1];
  const void* Wemb = d_in[2];
  const void* bemb = d_in[3];
  const void* W1 = d_in[4];
  const void* b1 = d_in[5];
  const void* W2 = d_in[6];
  const void* b2 = d_in[7];
  const void* W3 = d_in[8];
  const void* b3 = d_in[9];

  char* p = (char*)d_ws;
  float* dis = (float*)p;   p += NN * sizeof(float);
  float* bvec = (float*)p;  p += HH * sizeof(float);
  u16* TWc = (u16*)p;       p += (size_t)HH * FN * 2;
  u16* WembB = (u16*)p;     p += (size_t)FN * HH * 2;
  u16* TW1 = (u16*)p;       p += (size_t)HH * HH * 2;
  u16* TW2 = (u16*)p;       p += (size_t)HH * HH * 2;
  u16* TW3 = (u16*)p;       p += (size_t)HH * HH * 2;
  u16* xA = (u16*)p;        p += (size_t)NN * HH * 2;  // 8 MB GEMM-out buffer
  u32* bar = (u32*)p;       // grid-barrier counter (zeroed per launch)

  hipMemsetAsync(bar, 0, 128, stream);
  mega_kernel<<<NBLK, 256, 0, stream>>>(node, idxw, Wemb, bemb, W1, b1, W2, b2,
                                        W3, b3, dis, bvec, TWc, WembB, TW1,
                                        TW2, TW3, xA, bar, d_out);
}

// Round 3
// 479.182 us; speedup vs baseline: 2.3947x; 2.3947x over previous
//
#include <hip/hip_runtime.h>
#include <stdint.h>

#define NN 8192
#define MM 16
#define FN 128
#define HH 512
#define NBLK 512

typedef unsigned short u16;
typedef unsigned int u32;
typedef __bf16 bf16;
typedef __bf16 bf16x8 __attribute__((ext_vector_type(8)));
typedef float f32x4 __attribute__((ext_vector_type(4)));

// async global->LDS, 16B/lane; LDS dest = wave-uniform base + lane*16
__device__ __forceinline__ void gld_lds16(const u16* g, u16* l) {
  __builtin_amdgcn_global_load_lds(
      (const __attribute__((address_space(1))) void*)g,
      (__attribute__((address_space(3))) void*)l, 16, 0, 0);
}

// ---- software grid barrier: monotonic agent-scope counter, no reset ----
// All NBLK blocks co-resident (__launch_bounds__(256,2), 24KB LDS -> 2/CU).
// KEY (R2 post-mortem): poll must be RELAXED — an agent-scope ACQUIRE load
// emits buffer_inv (L1+L2 shoot-down) PER POLL, which nuked all cache
// locality grid-wide (1134us, 1.5% VALUBusy). One acquire fence after the
// wait exits is sufficient: release side is carried by fetch_add(RELEASE)
// (wbl2 before the add; __syncthreads already drained all waves' stores).
__device__ __forceinline__ void grid_bar(u32* bar, u32 target) {
  __syncthreads();  // all waves done; stores drained (vmcnt(0) before barrier)
  if (threadIdx.x == 0) {
    __hip_atomic_fetch_add(bar, 1u, __ATOMIC_RELEASE, __HIP_MEMORY_SCOPE_AGENT);
    while (__hip_atomic_load(bar, __ATOMIC_RELAXED, __HIP_MEMORY_SCOPE_AGENT) <
           target)
      __builtin_amdgcn_s_sleep(8);
    __builtin_amdgcn_fence(__ATOMIC_ACQUIRE, "agent");  // one L1/L2 inv
  }
  __syncthreads();
}

// ---- dtype probes (per-wave; ~2 cached loads + ballot) ----
__device__ __forceinline__ int probe_f32(const u16* w) {
  int lane = threadIdx.x & 63;
  int e = (w[2 * lane] >> 7) & 0xFF;
  unsigned long long m = __ballot(!(e == 0 || (e >= 90 && e <= 140)));
  return __popcll(m) >= 8;
}
__device__ __forceinline__ int probe_i64(const u32* w) {
  int lane = threadIdx.x & 63;
  unsigned long long m = __ballot(lane < 32 && w[2 * lane + 1] != 0);
  return m == 0;
}

__device__ __forceinline__ bf16 cvt_elem(const void* p, size_t i, int f32) {
  return f32 ? (bf16)((const float*)p)[i] : ((const bf16*)p)[i];
}

// ---- transpose one 32x32 tile of W (512 x 512) -> T (512 x 512) ----
__device__ __forceinline__ void transpose_tile(const void* __restrict__ W,
                                               u16* __restrict__ T, int tt,
                                               int f32in, u16* sm) {
  const int k0 = (tt >> 4) * 32, n0 = (tt & 15) * 32;
  const int tx = threadIdx.x & 31, ty = threadIdx.x >> 5;  // ty 0..7
#pragma unroll
  for (int r = ty; r < 32; r += 8) {
    bf16 v = cvt_elem(W, (size_t)(k0 + r) * HH + n0 + tx, f32in);
    sm[r * 33 + tx] = *(u16*)&v;
  }
  __syncthreads();
#pragma unroll
  for (int r = ty; r < 32; r += 8)
    T[(size_t)(n0 + r) * HH + k0 + tx] = sm[tx * 33 + r];
}

// ---- GEMM tile: C[rtile*64..+64][ctile*128..+128] = A @ Bt^T (+ biasf)
// 256 thr / 4 waves (2x2), wave 32x64 (2x4 accs of 16x16x32), BK=64,
// gld_lds + XOR swizzle (LDS chunk (row,cc) holds k-chunk gc = cc^(row&7)).
// Verified: correct, 0 bank conflicts. Writes bf16, row stride cstride.
__device__ __forceinline__ void gemm_tile(const void* __restrict__ A, int K,
                                          int af32, const u16* __restrict__ Bt,
                                          const float* __restrict__ biasf,
                                          int rtile, int ctile,
                                          u16* __restrict__ C, int cstride,
                                          u16* As, u16* Bs) {
  const int tid = threadIdx.x;
  const int wave = tid >> 6, lane = tid & 63;
  const int wr = wave >> 1, wc = wave & 1;
  const int quad = lane >> 4, l16 = lane & 15;
  f32x4 acc[2][4] = {};

  int arow[2], agc[2], brow[4], bgc[4];
#pragma unroll
  for (int i = 0; i < 2; ++i) {
    int c = i * 256 + tid;
    arow[i] = c >> 3;
    agc[i] = (c & 7) ^ (arow[i] & 7);
  }
#pragma unroll
  for (int i = 0; i < 4; ++i) {
    int c = i * 256 + tid;
    brow[i] = c >> 3;
    bgc[i] = (c & 7) ^ (brow[i] & 7);
  }
  u16* AsW = As + wave * 512;  // wave-uniform LDS bases (chunk c -> c*16 B)
  u16* BsW = Bs + wave * 512;

  for (int k0 = 0; k0 < K; k0 += 64) {
    __syncthreads();  // prev iter's ds_reads done
    if (af32) {
      const float* Af = (const float*)A;
      bf16x8 v[2];
#pragma unroll
      for (int i = 0; i < 2; ++i) {
        const float* p = &Af[(size_t)(rtile * 64 + arow[i]) * K + k0 + agc[i] * 8];
        f32x4 x0 = *(const f32x4*)p, x1 = *(const f32x4*)(p + 4);
#pragma unroll
        for (int t = 0; t < 4; ++t) {
          v[i][t] = (bf16)x0[t];
          v[i][4 + t] = (bf16)x1[t];
        }
      }
#pragma unroll
      for (int i = 0; i < 2; ++i) *(bf16x8*)&As[(i * 256 + tid) * 8] = v[i];
    } else {
      const u16* Ab = (const u16*)A;
#pragma unroll
      for (int i = 0; i < 2; ++i)
        gld_lds16(&Ab[(size_t)(rtile * 64 + arow[i]) * K + k0 + agc[i] * 8],
                  AsW + i * 2048);
    }
#pragma unroll
    for (int i = 0; i < 4; ++i)
      gld_lds16(&Bt[(size_t)(ctile * 128 + brow[i]) * K + k0 + bgc[i] * 8],
                BsW + i * 2048);
    __syncthreads();  // drains vmcnt (DMA complete)
#pragma unroll
    for (int h = 0; h < 2; ++h) {
      bf16x8 af[2], bfr[4];
#pragma unroll
      for (int i = 0; i < 2; ++i) {
        int r = wr * 32 + i * 16 + l16;
        int cc = (h * 4 + quad) ^ (r & 7);
        af[i] = *(const bf16x8*)&As[r * 64 + cc * 8];
      }
#pragma unroll
      for (int j = 0; j < 4; ++j) {
        int n = wc * 64 + j * 16 + l16;
        int cc = (h * 4 + quad) ^ (n & 7);
        bfr[j] = *(const bf16x8*)&Bs[n * 64 + cc * 8];
      }
#pragma unroll
      for (int i = 0; i < 2; ++i)
#pragma unroll
        for (int j = 0; j < 4; ++j)
          acc[i][j] = __builtin_amdgcn_mfma_f32_16x16x32_bf16(af[i], bfr[j],
                                                              acc[i][j], 0, 0, 0);
    }
  }

  // C/D layout: col = lane&15, row = quad*4 + reg (m89/m91)
  const int crow0 = rtile * 64 + wr * 32 + quad * 4;
  const int ccol0 = ctile * 128 + wc * 64 + l16;
#pragma unroll
  for (int j = 0; j < 4; ++j) {
    const int col = ccol0 + j * 16;
    const float bv = biasf ? biasf[col] : 0.f;
#pragma unroll
    for (int i = 0; i < 2; ++i)
#pragma unroll
      for (int r = 0; r < 4; ++r) {
        bf16 o = (bf16)(acc[i][j][r] + bv);
        C[(size_t)(crow0 + i * 16 + r) * cstride + col] = *(u16*)&o;
      }
  }
}

// ---- agg x4: block b processes units {b, b+512, b+1024, b+1536} INTERLEAVED
// (same strip/c0 for all 4 since 512%8==0; nodes differ by 2048r).
// Interleaving gives 4x the in-flight gather loads — needed because the
// persistent grid runs agg at 8 waves/CU vs 32 in the multi-kernel version.
// y[i,:] = act( d[i]*( d[i]*t[i,:] + sum_j d[j]*t[j,:] ) + b )
template <bool RELU, bool FINAL>
__device__ __forceinline__ void agg_quad(int b, const u16* __restrict__ t,
                                         const int* __restrict__ idx, int i64,
                                         const float* __restrict__ dis,
                                         const void* __restrict__ bias,
                                         int f32io, void* __restrict__ y) {
  const int strip = (b & 7) >> 1;          // 0..3, pinned to XCD pair
  const int grp0 = (b >> 3) * 2 + (b & 1);  // 0..127 base node group
  const int wave = threadIdx.x >> 6, lane = threadIdx.x & 63;
  const int node0 = grp0 * 16 + wave * 4 + (lane >> 4);
  const int c0 = strip * 128 + (lane & 15) * 8;

  float wi[4];
  float acc[4][8];
#pragma unroll
  for (int r = 0; r < 4; ++r) {
    const int node = node0 + 2048 * r;
    wi[r] = dis[node];
    bf16x8 xs = *(const bf16x8*)&t[(size_t)node * HH + c0];
#pragma unroll
    for (int k = 0; k < 8; ++k) acc[r][k] = wi[r] * wi[r] * (float)xs[k];
  }
#pragma unroll
  for (int e = 0; e < MM; ++e) {
    int j[4];
#pragma unroll
    for (int r = 0; r < 4; ++r)
      j[r] = idx[(((node0 + 2048 * r) * MM) + e) << i64];
#pragma unroll
    for (int r = 0; r < 4; ++r) {
      if (j[r] >= 0) {
        const float w = wi[r] * dis[j[r]];
        bf16x8 v = *(const bf16x8*)&t[(size_t)j[r] * HH + c0];
#pragma unroll
        for (int k = 0; k < 8; ++k) acc[r][k] += w * (float)v[k];
      }
    }
  }

  float bv[8];
  if (f32io) {
    f32x4 b0 = *(const f32x4*)&((const float*)bias)[c0];
    f32x4 b1 = *(const f32x4*)&((const float*)bias)[c0 + 4];
#pragma unroll
    for (int k = 0; k < 4; ++k) { bv[k] = b0[k]; bv[4 + k] = b1[k]; }
  } else {
    bf16x8 bb = *(const bf16x8*)&((const u16*)bias)[c0];
#pragma unroll
    for (int k = 0; k < 8; ++k) bv[k] = (float)bb[k];
  }
#pragma unroll
  for (int r = 0; r < 4; ++r) {
    const int node = node0 + 2048 * r;
    float o[8];
#pragma unroll
    for (int k = 0; k < 8; ++k) {
      o[k] = acc[r][k] + bv[k];
      if (RELU) o[k] = fmaxf(o[k], 0.f);
    }
    if (FINAL && f32io) {
      float* O = (float*)y;
      f32x4 o0, o1;
#pragma unroll
      for (int k = 0; k < 4; ++k) { o0[k] = o[k]; o1[k] = o[4 + k]; }
      *(f32x4*)&O[(size_t)node * HH + c0] = o0;
      *(f32x4*)&O[(size_t)node * HH + c0 + 4] = o1;
    } else {
      bf16x8 ob;
#pragma unroll
      for (int k = 0; k < 8; ++k) ob[k] = (bf16)o[k];
      *(bf16x8*)&((u16*)y)[(size_t)node * HH + c0] = ob;
    }
  }
}

// ---- single persistent kernel: the whole pipeline, 7 software grid syncs --
// 512 blocks x 256 thr; 24KB LDS + VGPR<=256 ((256,2)) => 2 blocks/CU,
// all 512 co-resident.
__global__ __launch_bounds__(256, 2) void mega_kernel(
    const u16* __restrict__ node, const u32* __restrict__ idxw,
    const void* __restrict__ Wemb, const void* __restrict__ bemb,
    const void* __restrict__ W1, const void* __restrict__ b1,
    const void* __restrict__ W2, const void* __restrict__ b2,
    const void* __restrict__ W3, const void* __restrict__ b3,
    float* __restrict__ dis, float* __restrict__ bvec, u16* __restrict__ TWc,
    u16* __restrict__ WembB, u16* __restrict__ TW1, u16* __restrict__ TW2,
    u16* __restrict__ TW3, u16* __restrict__ xA, u32* __restrict__ bar,
    void* __restrict__ outp) {
  __shared__ __align__(16) u16 As[64 * 64];
  __shared__ __align__(16) u16 Bs[128 * 64];
  const int bid = blockIdx.x, tid = threadIdx.x;
  const int f32in = probe_f32(node);
  const int i64 = probe_i64(idxw);
  const int* idx = (const int*)idxw;
  u16* xO = (u16*)outp;  // d_out doubles as bf16 ping buffer

  // ---- P1: transposes (0..767) + WembB copy (768..799) + dis (800..831)
  for (int u = bid; u < 832; u += NBLK) {
    if (u < 768) {
      const int q = u >> 8, tt = u & 255;
      transpose_tile(q == 0 ? W1 : q == 1 ? W2 : W3,
                     q == 0 ? TW1 : q == 1 ? TW2 : TW3, tt, f32in, As);
      __syncthreads();  // sm (=As) reuse guard across loop iters
    } else if (u < 800) {
      const size_t g = ((size_t)(u - 768) * 256 + tid) * 8;  // 8 elems/thread
      bf16x8 o;
      if (f32in) {
        f32x4 a = *(const f32x4*)&((const float*)Wemb)[g];
        f32x4 bq = *(const f32x4*)&((const float*)Wemb)[g + 4];
#pragma unroll
        for (int t = 0; t < 4; ++t) { o[t] = (bf16)a[t]; o[4 + t] = (bf16)bq[t]; }
      } else {
        o = *(const bf16x8*)&((const u16*)Wemb)[g];
      }
      *(bf16x8*)&WembB[g] = o;
    } else {
      const int i = (u - 800) * 256 + tid;
      int c = 1;
#pragma unroll
      for (int e = 0; e < MM; ++e) c += (idx[(i * MM + e) << i64] >= 0) ? 1 : 0;
      dis[i] = rsqrtf((float)c);
    }
  }
  grid_bar(bar, 1 * NBLK);

  // ---- P2: TWc = TW1 @ Wemb^T (blocks 0..7) + bvec (8..9)
  if (bid < 8) {
    const u16* Bt = f32in ? WembB : (const u16*)Wemb;
    gemm_tile(TW1, HH, 0, Bt, nullptr, bid, 0, TWc, FN, As, Bs);
  } else if (bid < 10) {
    float* bembS = (float*)Bs;
    bembS[tid] = (float)cvt_elem(bemb, tid, f32in);
    bembS[256 + tid] = (float)cvt_elem(bemb, 256 + tid, f32in);
    __syncthreads();
    const int n = (bid - 8) * 256 + tid;  // 0..511
    float acc = 0.f;
#pragma unroll 8
    for (int m = 0; m < HH; m += 8) {
      bf16x8 w = *(const bf16x8*)&TW1[(size_t)n * HH + m];
#pragma unroll
      for (int jj = 0; jj < 8; ++jj) acc += bembS[m + jj] * (float)w[jj];
    }
    bvec[n] = acc;
  }
  grid_bar(bar, 2 * NBLK);

  // ---- P3: g1: xA = node @ TWc^T + bvec  (K=128, A maybe fp32)
  gemm_tile(node, FN, f32in, TWc, bvec, bid & 127, bid >> 7, xA, HH, As, Bs);
  grid_bar(bar, 3 * NBLK);

  // ---- P4: agg1 + relu
  agg_quad<true, false>(bid, xA, idx, i64, dis, b1, f32in, xO);
  grid_bar(bar, 4 * NBLK);

  // ---- P5: gemm2: xA = xO @ TW2^T
  gemm_tile(xO, HH, 0, TW2, nullptr, bid & 127, bid >> 7, xA, HH, As, Bs);
  grid_bar(bar, 5 * NBLK);

  // ---- P6: agg2 + relu
  agg_quad<true, false>(bid, xA, idx, i64, dis, b2, f32in, xO);
  grid_bar(bar, 6 * NBLK);

  // ---- P7: gemm3: xA = xO @ TW3^T
  gemm_tile(xO, HH, 0, TW3, nullptr, bid & 127, bid >> 7, xA, HH, As, Bs);
  grid_bar(bar, 7 * NBLK);

  // ---- P8: agg3 (no relu, final dtype-matched store to d_out)
  agg_quad<false, true>(bid, xA, idx, i64, dis, b3, f32in, outp);
}

extern "C" void kernel_launch(void* const* d_in, const int* in_sizes, int n_in,
                              void* d_out, int out_size, void* d_ws, size_t ws_size,
                              hipStream_t stream) {
  const u16* node = (const u16*)d_in[0];
  const u32* idxw = (const u32*)d_in[1];
  const void* Wemb = d_in[2];
  const void* bemb = d_in[3];
  const void* W1 = d_in[4];
  const void* b1 = d_in[5];
  const void* W2 = d_in[6];
  const void* b2 = d_in[7];
  const void* W3 = d_in[8];
  const void* b3 = d_in[9];

  char* p = (char*)d_ws;
  float* dis = (float*)p;   p += NN * sizeof(float);
  float* bvec = (float*)p;  p += HH * sizeof(float);
  u16* TWc = (u16*)p;       p += (size_t)HH * FN * 2;
  u16* WembB = (u16*)p;     p += (size_t)FN * HH * 2;
  u16* TW1 = (u16*)p;       p += (size_t)HH * HH * 2;
  u16* TW2 = (u16*)p;       p += (size_t)HH * HH * 2;
  u16* TW3 = (u16*)p;       p += (size_t)HH * HH * 2;
  u16* xA = (u16*)p;        p += (size_t)NN * HH * 2;  // 8 MB GEMM-out buffer
  u32* bar = (u32*)p;       // grid-barrier counter (zeroed per launch)

  hipMemsetAsync(bar, 0, 128, stream);
  mega_kernel<<<NBLK, 256, 0, stream>>>(node, idxw, Wemb, bemb, W1, b1, W2, b2,
                                        W3, b3, dis, bvec, TWc, WembB, TW1,
                                        TW2, TW3, xA, bar, d_out);
}

// Round 5
// 283.269 us; speedup vs baseline: 4.0509x; 1.6916x over previous
//
#include <hip/hip_runtime.h>
#include <stdint.h>

#define NN 8192
#define MM 16
#define FN 128
#define HH 512
#define NBLK 512

typedef unsigned short u16;
typedef unsigned int u32;
typedef __bf16 bf16;
typedef __bf16 bf16x8 __attribute__((ext_vector_type(8)));
typedef float f32x4 __attribute__((ext_vector_type(4)));

#define SCOPE_AGENT __HIP_MEMORY_SCOPE_AGENT

// async global->LDS, 16B/lane; LDS dest = wave-uniform base + lane*16
__device__ __forceinline__ void gld_lds16(const u16* g, u16* l) {
  __builtin_amdgcn_global_load_lds(
      (const __attribute__((address_space(1))) void*)g,
      (__attribute__((address_space(3))) void*)l, 16, 0, 0);
}

// ================= hierarchical grid barrier (R5) =====================
// R3: every block did RELEASE(wbl2)+ACQUIRE(inv) per barrier -> 2x512 L2
// walks, ~50us/barrier, and invalidates kept all phases cold. R4: nt
// stores are only an LRU hint (dirty lines stay in writer L2) -> stale.
// Correct minimal protocol:
//  * startup: per-block buffer_inv (L1) + ONE leader per XCD does agent
//    ACQUIRE (L2 inv) -> clears poison-fill / prev-launch residue.
//  * per barrier: arrive on per-XCD counter (8 parallel lines); the LAST
//    arriver on each XCD does ONE RELEASE add (buffer_wbl2 sc1 publishes
//    all co-XCD stores, which __syncthreads already drained into L2).
//    Readers poll one counter for nxcd publishes. NO invalidates needed:
//    intermediates are single-write buffers, so no XCD ever re-reads an
//    address it cached before the write (startup inv killed old copies).
// ctl layout (u32): [0]=c2  [8..15]=xpop  [16..23]=xcnt0  [24..79]=xarr[1..7][8]
struct BarSt {
  int xcd;
  u32 Bx, nxcd, ctgt;
};

__device__ __forceinline__ void bar_start(u32* ctl, BarSt& s) {
  // pre (issued before entry): tid0 added xpop[xcd]; wave0 buffer_inv (L1)
  __syncthreads();  // drains vmcnt: xpop add + buffer_inv complete
  if (threadIdx.x == 0) {
    u32* c2 = ctl;
    u32* xpop = ctl + 8;
    u32* xcnt0 = ctl + 16;
    u32 tot;
    do {  // all-arrive: sum of per-XCD populations
      tot = 0;
#pragma unroll
      for (int x = 0; x < 8; ++x)
        tot += __hip_atomic_load(&xpop[x], __ATOMIC_RELAXED, SCOPE_AGENT);
      if (tot < NBLK) __builtin_amdgcn_s_sleep(4);
    } while (tot < NBLK);
    s.nxcd = 0;
#pragma unroll
    for (int x = 0; x < 8; ++x)
      s.nxcd += (__hip_atomic_load(&xpop[x], __ATOMIC_RELAXED, SCOPE_AGENT) != 0);
    s.Bx = __hip_atomic_load(&xpop[s.xcd], __ATOMIC_RELAXED, SCOPE_AGENT);
    if (__hip_atomic_fetch_add(&xcnt0[s.xcd], 1u, __ATOMIC_RELAXED,
                               SCOPE_AGENT) == 0) {
      __builtin_amdgcn_fence(__ATOMIC_ACQUIRE, "agent");  // L2 inv, this XCD
      asm volatile("s_waitcnt vmcnt(0)" ::: "memory");    // inv complete
      __hip_atomic_fetch_add(c2, 1u, __ATOMIC_RELEASE, SCOPE_AGENT);
    }
    s.ctgt = s.nxcd;
    while (__hip_atomic_load(c2, __ATOMIC_RELAXED, SCOPE_AGENT) < s.ctgt)
      __builtin_amdgcn_s_sleep(4);
  }
  __syncthreads();
  asm volatile("" ::: "memory");
}

__device__ __forceinline__ void bar_phase(u32* ctl, int k, BarSt& s) {
  __syncthreads();  // all waves' stores drained to local L2 (vmcnt(0))
  if (threadIdx.x == 0) {
    u32* c2 = ctl;
    u32* xarr = ctl + 24 + (k - 1) * 8;  // k = 1..7
    if (__hip_atomic_fetch_add(&xarr[s.xcd], 1u, __ATOMIC_RELAXED,
                               SCOPE_AGENT) == s.Bx - 1)  // last on my XCD
      __hip_atomic_fetch_add(c2, 1u, __ATOMIC_RELEASE, SCOPE_AGENT);  // wbl2
    s.ctgt += s.nxcd;
    while (__hip_atomic_load(c2, __ATOMIC_RELAXED, SCOPE_AGENT) < s.ctgt)
      __builtin_amdgcn_s_sleep(4);
  }
  __syncthreads();
  asm volatile("" ::: "memory");
}

// ---- dtype probes (per-wave; ~2 cached loads + ballot) ----
__device__ __forceinline__ int probe_f32(const u16* w) {
  int lane = threadIdx.x & 63;
  int e = (w[2 * lane] >> 7) & 0xFF;
  unsigned long long m = __ballot(!(e == 0 || (e >= 90 && e <= 140)));
  return __popcll(m) >= 8;
}
__device__ __forceinline__ int probe_i64(const u32* w) {
  int lane = threadIdx.x & 63;
  unsigned long long m = __ballot(lane < 32 && w[2 * lane + 1] != 0);
  return m == 0;
}

__device__ __forceinline__ bf16 cvt_elem(const void* p, size_t i, int f32) {
  return f32 ? (bf16)((const float*)p)[i] : ((const bf16*)p)[i];
}

// ---- transpose one 32x32 tile of W (512 x 512) -> T (512 x 512) ----
__device__ __forceinline__ void transpose_tile(const void* __restrict__ W,
                                               u16* __restrict__ T, int tt,
                                               int f32in, u16* sm) {
  const int k0 = (tt >> 4) * 32, n0 = (tt & 15) * 32;
  const int tx = threadIdx.x & 31, ty = threadIdx.x >> 5;  // ty 0..7
#pragma unroll
  for (int r = ty; r < 32; r += 8) {
    bf16 v = cvt_elem(W, (size_t)(k0 + r) * HH + n0 + tx, f32in);
    sm[r * 33 + tx] = *(u16*)&v;
  }
  __syncthreads();
#pragma unroll
  for (int r = ty; r < 32; r += 8)
    T[(size_t)(n0 + r) * HH + k0 + tx] = sm[tx * 33 + r];
}

// ---- GEMM tile: C[rtile*64..+64][ctile*128..+128] = A @ Bt^T (+ biasf)
// 256 thr / 4 waves (2x2), wave 32x64 (2x4 accs of 16x16x32), BK=64,
// gld_lds + XOR swizzle (LDS chunk (row,cc) holds k-chunk gc = cc^(row&7)).
// Verified: correct, 0 bank conflicts. Writes bf16, row stride cstride.
__device__ __forceinline__ void gemm_tile(const void* __restrict__ A, int K,
                                          int af32, const u16* __restrict__ Bt,
                                          const float* __restrict__ biasf,
                                          int rtile, int ctile,
                                          u16* __restrict__ C, int cstride,
                                          u16* As, u16* Bs) {
  const int tid = threadIdx.x;
  const int wave = tid >> 6, lane = tid & 63;
  const int wr = wave >> 1, wc = wave & 1;
  const int quad = lane >> 4, l16 = lane & 15;
  f32x4 acc[2][4] = {};

  int arow[2], agc[2], brow[4], bgc[4];
#pragma unroll
  for (int i = 0; i < 2; ++i) {
    int c = i * 256 + tid;
    arow[i] = c >> 3;
    agc[i] = (c & 7) ^ (arow[i] & 7);
  }
#pragma unroll
  for (int i = 0; i < 4; ++i) {
    int c = i * 256 + tid;
    brow[i] = c >> 3;
    bgc[i] = (c & 7) ^ (brow[i] & 7);
  }
  u16* AsW = As + wave * 512;  // wave-uniform LDS bases (chunk c -> c*16 B)
  u16* BsW = Bs + wave * 512;

  for (int k0 = 0; k0 < K; k0 += 64) {
    __syncthreads();  // prev iter's ds_reads done
    if (af32) {
      const float* Af = (const float*)A;
      bf16x8 v[2];
#pragma unroll
      for (int i = 0; i < 2; ++i) {
        const float* p = &Af[(size_t)(rtile * 64 + arow[i]) * K + k0 + agc[i] * 8];
        f32x4 x0 = *(const f32x4*)p, x1 = *(const f32x4*)(p + 4);
#pragma unroll
        for (int t = 0; t < 4; ++t) {
          v[i][t] = (bf16)x0[t];
          v[i][4 + t] = (bf16)x1[t];
        }
      }
#pragma unroll
      for (int i = 0; i < 2; ++i) *(bf16x8*)&As[(i * 256 + tid) * 8] = v[i];
    } else {
      const u16* Ab = (const u16*)A;
#pragma unroll
      for (int i = 0; i < 2; ++i)
        gld_lds16(&Ab[(size_t)(rtile * 64 + arow[i]) * K + k0 + agc[i] * 8],
                  AsW + i * 2048);
    }
#pragma unroll
    for (int i = 0; i < 4; ++i)
      gld_lds16(&Bt[(size_t)(ctile * 128 + brow[i]) * K + k0 + bgc[i] * 8],
                BsW + i * 2048);
    __syncthreads();  // drains vmcnt (DMA complete)
#pragma unroll
    for (int h = 0; h < 2; ++h) {
      bf16x8 af[2], bfr[4];
#pragma unroll
      for (int i = 0; i < 2; ++i) {
        int r = wr * 32 + i * 16 + l16;
        int cc = (h * 4 + quad) ^ (r & 7);
        af[i] = *(const bf16x8*)&As[r * 64 + cc * 8];
      }
#pragma unroll
      for (int j = 0; j < 4; ++j) {
        int n = wc * 64 + j * 16 + l16;
        int cc = (h * 4 + quad) ^ (n & 7);
        bfr[j] = *(const bf16x8*)&Bs[n * 64 + cc * 8];
      }
#pragma unroll
      for (int i = 0; i < 2; ++i)
#pragma unroll
        for (int j = 0; j < 4; ++j)
          acc[i][j] = __builtin_amdgcn_mfma_f32_16x16x32_bf16(af[i], bfr[j],
                                                              acc[i][j], 0, 0, 0);
    }
  }

  // C/D layout: col = lane&15, row = quad*4 + reg (m89/m91)
  const int crow0 = rtile * 64 + wr * 32 + quad * 4;
  const int ccol0 = ctile * 128 + wc * 64 + l16;
#pragma unroll
  for (int j = 0; j < 4; ++j) {
    const int col = ccol0 + j * 16;
    const float bv = biasf ? biasf[col] : 0.f;
#pragma unroll
    for (int i = 0; i < 2; ++i)
#pragma unroll
      for (int r = 0; r < 4; ++r) {
        bf16 o = (bf16)(acc[i][j][r] + bv);
        C[(size_t)(crow0 + i * 16 + r) * cstride + col] = *(u16*)&o;
      }
  }
}

// ---- agg x4: block b processes units {b, b+512, b+1024, b+1536} INTERLEAVED
// (same strip/c0 for all 4 since 512%8==0; nodes differ by 2048r).
// y[i,:] = act( d[i]*( d[i]*t[i,:] + sum_j d[j]*t[j,:] ) + b )
template <bool RELU, bool FINAL>
__device__ __forceinline__ void agg_quad(int b, const u16* __restrict__ t,
                                         const int* __restrict__ idx, int i64,
                                         const float* __restrict__ dis,
                                         const void* __restrict__ bias,
                                         int f32io, void* __restrict__ y) {
  const int strip = (b & 7) >> 1;           // 0..3, pinned to XCD pair
  const int grp0 = (b >> 3) * 2 + (b & 1);  // 0..127 base node group
  const int wave = threadIdx.x >> 6, lane = threadIdx.x & 63;
  const int node0 = grp0 * 16 + wave * 4 + (lane >> 4);
  const int c0 = strip * 128 + (lane & 15) * 8;

  float wi[4];
  float acc[4][8];
#pragma unroll
  for (int r = 0; r < 4; ++r) {
    const int node = node0 + 2048 * r;
    wi[r] = dis[node];
    bf16x8 xs = *(const bf16x8*)&t[(size_t)node * HH + c0];
#pragma unroll
    for (int k = 0; k < 8; ++k) acc[r][k] = wi[r] * wi[r] * (float)xs[k];
  }
#pragma unroll
  for (int e = 0; e < MM; ++e) {
    int j[4];
#pragma unroll
    for (int r = 0; r < 4; ++r)
      j[r] = idx[(((node0 + 2048 * r) * MM) + e) << i64];
#pragma unroll
    for (int r = 0; r < 4; ++r) {
      if (j[r] >= 0) {
        const float w = wi[r] * dis[j[r]];
        bf16x8 v = *(const bf16x8*)&t[(size_t)j[r] * HH + c0];
#pragma unroll
        for (int k = 0; k < 8; ++k) acc[r][k] += w * (float)v[k];
      }
    }
  }

  float bv[8];
  if (f32io) {
    f32x4 b0 = *(const f32x4*)&((const float*)bias)[c0];
    f32x4 b1 = *(const f32x4*)&((const float*)bias)[c0 + 4];
#pragma unroll
    for (int k = 0; k < 4; ++k) { bv[k] = b0[k]; bv[4 + k] = b1[k]; }
  } else {
    bf16x8 bb = *(const bf16x8*)&((const u16*)bias)[c0];
#pragma unroll
    for (int k = 0; k < 8; ++k) bv[k] = (float)bb[k];
  }
#pragma unroll
  for (int r = 0; r < 4; ++r) {
    const int node = node0 + 2048 * r;
    float o[8];
#pragma unroll
    for (int k = 0; k < 8; ++k) {
      o[k] = acc[r][k] + bv[k];
      if (RELU) o[k] = fmaxf(o[k], 0.f);
    }
    if (FINAL && f32io) {
      float* O = (float*)y;
      f32x4 o0, o1;
#pragma unroll
      for (int k = 0; k < 4; ++k) { o0[k] = o[k]; o1[k] = o[4 + k]; }
      *(f32x4*)&O[(size_t)node * HH + c0] = o0;
      *(f32x4*)&O[(size_t)node * HH + c0 + 4] = o1;
    } else {
      bf16x8 ob;
#pragma unroll
      for (int k = 0; k < 8; ++k) ob[k] = (bf16)o[k];
      *(bf16x8*)&((u16*)y)[(size_t)node * HH + c0] = ob;
    }
  }
}

// ---- single persistent kernel: whole pipeline, hierarchical grid syncs ----
// 512 blocks x 256 thr; 24KB LDS + launch_bounds(256,2) => 2 blocks/CU,
// all 512 co-resident. All cross-phase buffers are single-write (no reuse).
__global__ __launch_bounds__(256, 2) void mega_kernel(
    const u16* __restrict__ node, const u32* __restrict__ idxw,
    const void* __restrict__ Wemb, const void* __restrict__ bemb,
    const void* __restrict__ W1, const void* __restrict__ b1,
    const void* __restrict__ W2, const void* __restrict__ b2,
    const void* __restrict__ W3, const void* __restrict__ b3,
    float* __restrict__ dis, float* __restrict__ bvec, u16* __restrict__ TWc,
    u16* __restrict__ WembB, u16* __restrict__ TW1, u16* __restrict__ TW2,
    u16* __restrict__ TW3, u16* __restrict__ x1, u16* __restrict__ xO1,
    u16* __restrict__ x2, u16* __restrict__ xO2, u16* __restrict__ x3,
    u32* __restrict__ ctl, void* __restrict__ outp) {
  __shared__ __align__(16) u16 As[64 * 64];
  __shared__ __align__(16) u16 Bs[128 * 64];
  const int bid = blockIdx.x, tid = threadIdx.x;
  const int f32in = probe_f32(node);
  const int i64 = probe_i64(idxw);
  const int* idx = (const int*)idxw;

  // ---- P0: coherence startup (L1 inv per CU; L2 inv per XCD by leader)
  BarSt bs{};
  if (tid == 0) {
    // HW_REG_XCC_ID = id 20, offset 0, width 4 (m09-verified on MI355X)
    bs.xcd = (int)(__builtin_amdgcn_s_getreg(6164) & 7u);
    __hip_atomic_fetch_add(&ctl[8 + bs.xcd], 1u, __ATOMIC_RELAXED, SCOPE_AGENT);
  }
  if (tid < 64) asm volatile("buffer_inv" ::: "memory");  // L1 of this CU
  bar_start(ctl, bs);

  // ---- P1: transposes (0..767) + WembB copy (768..799) + dis (800..831)
  for (int u = bid; u < 832; u += NBLK) {
    if (u < 768) {
      const int q = u >> 8, tt = u & 255;
      transpose_tile(q == 0 ? W1 : q == 1 ? W2 : W3,
                     q == 0 ? TW1 : q == 1 ? TW2 : TW3, tt, f32in, As);
      __syncthreads();  // sm (=As) reuse guard across loop iters
    } else if (u < 800) {
      const size_t g = ((size_t)(u - 768) * 256 + tid) * 8;  // 8 elems/thread
      bf16x8 o;
      if (f32in) {
        f32x4 a = *(const f32x4*)&((const float*)Wemb)[g];
        f32x4 bq = *(const f32x4*)&((const float*)Wemb)[g + 4];
#pragma unroll
        for (int t = 0; t < 4; ++t) { o[t] = (bf16)a[t]; o[4 + t] = (bf16)bq[t]; }
      } else {
        o = *(const bf16x8*)&((const u16*)Wemb)[g];
      }
      *(bf16x8*)&WembB[g] = o;
    } else {
      const int i = (u - 800) * 256 + tid;
      int c = 1;
#pragma unroll
      for (int e = 0; e < MM; ++e) c += (idx[(i * MM + e) << i64] >= 0) ? 1 : 0;
      dis[i] = rsqrtf((float)c);
    }
  }
  bar_phase(ctl, 1, bs);

  // ---- P2: TWc = TW1 @ Wemb^T (blocks 0..7) + bvec (8..9)
  if (bid < 8) {
    const u16* Bt = f32in ? WembB : (const u16*)Wemb;
    gemm_tile(TW1, HH, 0, Bt, nullptr, bid, 0, TWc, FN, As, Bs);
  } else if (bid < 10) {
    float* bembS = (float*)Bs;
    bembS[tid] = (float)cvt_elem(bemb, tid, f32in);
    bembS[256 + tid] = (float)cvt_elem(bemb, 256 + tid, f32in);
    __syncthreads();
    const int n = (bid - 8) * 256 + tid;  // 0..511
    float acc = 0.f;
#pragma unroll 8
    for (int m = 0; m < HH; m += 8) {
      bf16x8 w = *(const bf16x8*)&TW1[(size_t)n * HH + m];
#pragma unroll
      for (int jj = 0; jj < 8; ++jj) acc += bembS[m + jj] * (float)w[jj];
    }
    bvec[n] = acc;
  }
  bar_phase(ctl, 2, bs);

  // ---- P3: g1: x1 = node @ TWc^T + bvec  (K=128, A maybe fp32)
  gemm_tile(node, FN, f32in, TWc, bvec, bid & 127, bid >> 7, x1, HH, As, Bs);
  bar_phase(ctl, 3, bs);

  // ---- P4: agg1 + relu: xO1 = A~ x1
  agg_quad<true, false>(bid, x1, idx, i64, dis, b1, f32in, xO1);
  bar_phase(ctl, 4, bs);

  // ---- P5: gemm2: x2 = xO1 @ TW2^T
  gemm_tile(xO1, HH, 0, TW2, nullptr, bid & 127, bid >> 7, x2, HH, As, Bs);
  bar_phase(ctl, 5, bs);

  // ---- P6: agg2 + relu: xO2 = A~ x2
  agg_quad<true, false>(bid, x2, idx, i64, dis, b2, f32in, xO2);
  bar_phase(ctl, 6, bs);

  // ---- P7: gemm3: x3 = xO2 @ TW3^T
  gemm_tile(xO2, HH, 0, TW3, nullptr, bid & 127, bid >> 7, x3, HH, As, Bs);
  bar_phase(ctl, 7, bs);

  // ---- P8: agg3 (no relu, final dtype-matched store to d_out)
  agg_quad<false, true>(bid, x3, idx, i64, dis, b3, f32in, outp);
}

extern "C" void kernel_launch(void* const* d_in, const int* in_sizes, int n_in,
                              void* d_out, int out_size, void* d_ws, size_t ws_size,
                              hipStream_t stream) {
  const u16* node = (const u16*)d_in[0];
  const u32* idxw = (const u32*)d_in[1];
  const void* Wemb = d_in[2];
  const void* bemb = d_in[3];
  const void* W1 = d_in[4];
  const void* b1 = d_in[5];
  const void* W2 = d_in[6];
  const void* b2 = d_in[7];
  const void* W3 = d_in[8];
  const void* b3 = d_in[9];

  char* p = (char*)d_ws;
  float* dis = (float*)p;   p += NN * sizeof(float);
  float* bvec = (float*)p;  p += HH * sizeof(float);
  u16* TWc = (u16*)p;       p += (size_t)HH * FN * 2;
  u16* WembB = (u16*)p;     p += (size_t)FN * HH * 2;
  u16* TW1 = (u16*)p;       p += (size_t)HH * HH * 2;
  u16* TW2 = (u16*)p;       p += (size_t)HH * HH * 2;
  u16* TW3 = (u16*)p;       p += (size_t)HH * HH * 2;
  u16* x1 = (u16*)p;        p += (size_t)NN * HH * 2;  // single-write buffers
  u16* xO1 = (u16*)p;       p += (size_t)NN * HH * 2;
  u16* x2 = (u16*)p;        p += (size_t)NN * HH * 2;
  u16* xO2 = (u16*)p;       p += (size_t)NN * HH * 2;
  u16* x3 = (u16*)p;        p += (size_t)NN * HH * 2;
  u32* ctl = (u32*)p;       // barrier control block (zeroed per launch)

  hipMemsetAsync(ctl, 0, 512, stream);
  mega_kernel<<<NBLK, 256, 0, stream>>>(node, idxw, Wemb, bemb, W1, b1, W2, b2,
                                        W3, b3, dis, bvec, TWc, WembB, TW1,
                                        TW2, TW3, x1, xO1, x2, xO2, x3, ctl,
                                        d_out);
}

// Round 8
// 219.487 us; speedup vs baseline: 5.2280x; 1.2906x over previous
//
#include <hip/hip_runtime.h>
#include <stdint.h>

#define NN 8192
#define MM 16
#define FN 128
#define HH 512
#define NBLK 512

typedef unsigned short u16;
typedef unsigned int u32;
typedef __bf16 bf16;
typedef __bf16 bf16x8 __attribute__((ext_vector_type(8)));
typedef float f32x4 __attribute__((ext_vector_type(4)));

#define SCOPE_AGENT __HIP_MEMORY_SCOPE_AGENT

// async global->LDS, 16B/lane; LDS dest = wave-uniform base + lane*16
__device__ __forceinline__ void gld_lds16(const u16* g, u16* l) {
  __builtin_amdgcn_global_load_lds(
      (const __attribute__((address_space(1))) void*)g,
      (__attribute__((address_space(3))) void*)l, 16, 0, 0);
}

// ============ hierarchical grid barrier v4 (R8) — ALL memory-side =========
// R6/R7 hang post-mortem: both used sc0 (L2-served) polls of a PLAIN-stored
// flag; if the plain store lingers in the CU-local write path the sc0 poll
// never sees it -> infinite spin. R5's all-memory-side barrier ran 30+
// dispatches correctly. So: every ctl access here is a memory-side
// (__hip_atomic_*, agent scope, sc1) op — staleness-immune by construction.
// vs R5 (221us, ~20us/barrier): arrivals stay on per-XCD lines; ONLY the 8
// leaders poll c2 (R5 had 512 pollers queuing ahead of the publish adds);
// leaders re-broadcast via per-XCD ep lines (64 pollers/line, 8 lines).
// ctl (u32 idx, 128B-separated): [0]=c2 [32]=s2 [64+32x]=xpop
//   [320+32x]=xarr [576+32x]=ep (+1 Bx, +2 nxcd)
struct BarSt {
  int xcd, leader;
  u32 Bx, nxcd;
};

__device__ __forceinline__ void bar_start(u32* ctl, BarSt& s) {
  if (threadIdx.x < 64) {  // this CU's L1: stale lines from prior launches
    asm volatile("buffer_inv" ::: "memory");
    asm volatile("s_waitcnt vmcnt(0)" ::: "memory");
  }
  if (threadIdx.x == 0) {
    // HW_REG_XCC_ID = id 20, offset 0, width 4 (m09-verified on MI355X)
    s.xcd = (int)(__builtin_amdgcn_s_getreg(6164) & 7u);
    u32* xpop = ctl + 64 + 32 * s.xcd;
    u32* ep = ctl + 576 + 32 * s.xcd;
    u32 r = __hip_atomic_fetch_add(xpop, 1u, __ATOMIC_RELAXED, SCOPE_AGENT);
    s.leader = (r == 0);
    if (s.leader) {  // one L2 inv per XCD: kills poison/old-launch residue
      __builtin_amdgcn_fence(__ATOMIC_ACQUIRE, "agent");
      asm volatile("s_waitcnt vmcnt(0)" ::: "memory");
    }
    __hip_atomic_fetch_add(ctl + 32, 1u, __ATOMIC_RELAXED, SCOPE_AGENT);
    if (s.leader) {
      while (__hip_atomic_load(ctl + 32, __ATOMIC_RELAXED, SCOPE_AGENT) < NBLK)
        __builtin_amdgcn_s_sleep(8);
      u32 bx = 0, nx = 0;
#pragma unroll
      for (int x = 0; x < 8; ++x) {
        u32 v =
            __hip_atomic_load(ctl + 64 + 32 * x, __ATOMIC_RELAXED, SCOPE_AGENT);
        nx += (v != 0);
        if (x == s.xcd) bx = v;
      }
      s.Bx = bx;
      s.nxcd = nx;
      __hip_atomic_store(ep + 1, bx, __ATOMIC_RELAXED, SCOPE_AGENT);
      __hip_atomic_store(ep + 2, nx, __ATOMIC_RELAXED, SCOPE_AGENT);
      asm volatile("s_waitcnt vmcnt(0)" ::: "memory");  // +1/+2 done first
      __hip_atomic_store(ep, 1u, __ATOMIC_RELAXED, SCOPE_AGENT);
    } else {
      while (__hip_atomic_load(ep, __ATOMIC_RELAXED, SCOPE_AGENT) < 1u)
        __builtin_amdgcn_s_sleep(8);
      s.Bx = __hip_atomic_load(ep + 1, __ATOMIC_RELAXED, SCOPE_AGENT);
      s.nxcd = __hip_atomic_load(ep + 2, __ATOMIC_RELAXED, SCOPE_AGENT);
    }
  }
  __syncthreads();
  asm volatile("" ::: "memory");
}

__device__ __forceinline__ void bar_phase(u32* ctl, u32 k, BarSt& s) {
  __syncthreads();  // all waves' stores drained to local L2 (vmcnt(0))
  if (threadIdx.x == 0) {
    u32* xarr = ctl + 320 + 32 * s.xcd;
    u32* ep = ctl + 576 + 32 * s.xcd;
    u32 r = __hip_atomic_fetch_add(xarr, 1u, __ATOMIC_RELAXED, SCOPE_AGENT);
    if (r == k * s.Bx - 1)  // last arriver of phase k on this XCD
      __hip_atomic_fetch_add(ctl, 1u, __ATOMIC_RELEASE, SCOPE_AGENT);  // wbl2
    if (s.leader) {
      while (__hip_atomic_load(ctl, __ATOMIC_RELAXED, SCOPE_AGENT) <
             s.nxcd * k)
        __builtin_amdgcn_s_sleep(2);
      __hip_atomic_store(ep, k + 1, __ATOMIC_RELAXED, SCOPE_AGENT);
    } else {
      while (__hip_atomic_load(ep, __ATOMIC_RELAXED, SCOPE_AGENT) < k + 1)
        __builtin_amdgcn_s_sleep(2);
    }
  }
  __syncthreads();
  asm volatile("" ::: "memory");
}

// ---- dtype probes (per-wave; ~2 cached loads + ballot) ----
__device__ __forceinline__ int probe_f32(const u16* w) {
  int lane = threadIdx.x & 63;
  int e = (w[2 * lane] >> 7) & 0xFF;
  unsigned long long m = __ballot(!(e == 0 || (e >= 90 && e <= 140)));
  return __popcll(m) >= 8;
}
__device__ __forceinline__ int probe_i64(const u32* w) {
  int lane = threadIdx.x & 63;
  unsigned long long m = __ballot(lane < 32 && w[2 * lane + 1] != 0);
  return m == 0;
}

__device__ __forceinline__ bf16 cvt_elem(const void* p, size_t i, int f32) {
  return f32 ? (bf16)((const float*)p)[i] : ((const bf16*)p)[i];
}

// ---- transpose one 32x32 tile of W (512 x 512) -> T (512 x 512) ----
__device__ __forceinline__ void transpose_tile(const void* __restrict__ W,
                                               u16* __restrict__ T, int tt,
                                               int f32in, u16* sm) {
  const int k0 = (tt >> 4) * 32, n0 = (tt & 15) * 32;
  const int tx = threadIdx.x & 31, ty = threadIdx.x >> 5;  // ty 0..7
#pragma unroll
  for (int r = ty; r < 32; r += 8) {
    bf16 v = cvt_elem(W, (size_t)(k0 + r) * HH + n0 + tx, f32in);
    sm[r * 33 + tx] = *(u16*)&v;
  }
  __syncthreads();
#pragma unroll
  for (int r = ty; r < 32; r += 8)
    T[(size_t)(n0 + r) * HH + k0 + tx] = sm[tx * 33 + r];
}

// ---- GEMM tile: C[rtile*64..+64][ctile*128..+128] = A @ Bt^T (+ biasf)
// 256 thr / 4 waves (2x2), wave 32x64 (2x4 accs of 16x16x32), BK=64,
// gld_lds + XOR swizzle (LDS chunk (row,cc) holds k-chunk gc = cc^(row&7)).
// Verified: correct, 0 bank conflicts. Writes bf16, row stride cstride.
__device__ __forceinline__ void gemm_tile(const void* __restrict__ A, int K,
                                          int af32, const u16* __restrict__ Bt,
                                          const float* __restrict__ biasf,
                                          int rtile, int ctile,
                                          u16* __restrict__ C, int cstride,
                                          u16* As, u16* Bs) {
  const int tid = threadIdx.x;
  const int wave = tid >> 6, lane = tid & 63;
  const int wr = wave >> 1, wc = wave & 1;
  const int quad = lane >> 4, l16 = lane & 15;
  f32x4 acc[2][4] = {};

  int arow[2], agc[2], brow[4], bgc[4];
#pragma unroll
  for (int i = 0; i < 2; ++i) {
    int c = i * 256 + tid;
    arow[i] = c >> 3;
    agc[i] = (c & 7) ^ (arow[i] & 7);
  }
#pragma unroll
  for (int i = 0; i < 4; ++i) {
    int c = i * 256 + tid;
    brow[i] = c >> 3;
    bgc[i] = (c & 7) ^ (brow[i] & 7);
  }
  u16* AsW = As + wave * 512;  // wave-uniform LDS bases (chunk c -> c*16 B)
  u16* BsW = Bs + wave * 512;

  for (int k0 = 0; k0 < K; k0 += 64) {
    __syncthreads();  // prev iter's ds_reads done
    if (af32) {
      const float* Af = (const float*)A;
      bf16x8 v[2];
#pragma unroll
      for (int i = 0; i < 2; ++i) {
        const float* p = &Af[(size_t)(rtile * 64 + arow[i]) * K + k0 + agc[i] * 8];
        f32x4 x0 = *(const f32x4*)p, x1 = *(const f32x4*)(p + 4);
#pragma unroll
        for (int t = 0; t < 4; ++t) {
          v[i][t] = (bf16)x0[t];
          v[i][4 + t] = (bf16)x1[t];
        }
      }
#pragma unroll
      for (int i = 0; i < 2; ++i) *(bf16x8*)&As[(i * 256 + tid) * 8] = v[i];
    } else {
      const u16* Ab = (const u16*)A;
#pragma unroll
      for (int i = 0; i < 2; ++i)
        gld_lds16(&Ab[(size_t)(rtile * 64 + arow[i]) * K + k0 + agc[i] * 8],
                  AsW + i * 2048);
    }
#pragma unroll
    for (int i = 0; i < 4; ++i)
      gld_lds16(&Bt[(size_t)(ctile * 128 + brow[i]) * K + k0 + bgc[i] * 8],
                BsW + i * 2048);
    __syncthreads();  // drains vmcnt (DMA complete)
#pragma unroll
    for (int h = 0; h < 2; ++h) {
      bf16x8 af[2], bfr[4];
#pragma unroll
      for (int i = 0; i < 2; ++i) {
        int r = wr * 32 + i * 16 + l16;
        int cc = (h * 4 + quad) ^ (r & 7);
        af[i] = *(const bf16x8*)&As[r * 64 + cc * 8];
      }
#pragma unroll
      for (int j = 0; j < 4; ++j) {
        int n = wc * 64 + j * 16 + l16;
        int cc = (h * 4 + quad) ^ (n & 7);
        bfr[j] = *(const bf16x8*)&Bs[n * 64 + cc * 8];
      }
#pragma unroll
      for (int i = 0; i < 2; ++i)
#pragma unroll
        for (int j = 0; j < 4; ++j)
          acc[i][j] = __builtin_amdgcn_mfma_f32_16x16x32_bf16(af[i], bfr[j],
                                                              acc[i][j], 0, 0, 0);
    }
  }

  // C/D layout: col = lane&15, row = quad*4 + reg (m89/m91)
  const int crow0 = rtile * 64 + wr * 32 + quad * 4;
  const int ccol0 = ctile * 128 + wc * 64 + l16;
#pragma unroll
  for (int j = 0; j < 4; ++j) {
    const int col = ccol0 + j * 16;
    const float bv = biasf ? biasf[col] : 0.f;
#pragma unroll
    for (int i = 0; i < 2; ++i)
#pragma unroll
      for (int r = 0; r < 4; ++r) {
        bf16 o = (bf16)(acc[i][j][r] + bv);
        C[(size_t)(crow0 + i * 16 + r) * cstride + col] = *(u16*)&o;
      }
  }
}

// ---- agg x4: block b processes units {b, b+512, b+1024, b+1536} INTERLEAVED
// (same strip/c0 for all 4 since 512%8==0; nodes differ by 2048r).
// y[i,:] = act( d[i]*( d[i]*t[i,:] + sum_j d[j]*t[j,:] ) + b )
template <bool RELU, bool FINAL>
__device__ __forceinline__ void agg_quad(int b, const u16* __restrict__ t,
                                         const int* __restrict__ idx, int i64,
                                         const float* __restrict__ dis,
                                         const void* __restrict__ bias,
                                         int f32io, void* __restrict__ y) {
  const int strip = (b & 7) >> 1;           // 0..3, pinned to XCD pair
  const int grp0 = (b >> 3) * 2 + (b & 1);  // 0..127 base node group
  const int wave = threadIdx.x >> 6, lane = threadIdx.x & 63;
  const int node0 = grp0 * 16 + wave * 4 + (lane >> 4);
  const int c0 = strip * 128 + (lane & 15) * 8;

  float wi[4];
  float acc[4][8];
#pragma unroll
  for (int r = 0; r < 4; ++r) {
    const int node = node0 + 2048 * r;
    wi[r] = dis[node];
    bf16x8 xs = *(const bf16x8*)&t[(size_t)node * HH + c0];
#pragma unroll
    for (int k = 0; k < 8; ++k) acc[r][k] = wi[r] * wi[r] * (float)xs[k];
  }
#pragma unroll
  for (int e = 0; e < MM; ++e) {
    int j[4];
#pragma unroll
    for (int r = 0; r < 4; ++r)
      j[r] = idx[(((node0 + 2048 * r) * MM) + e) << i64];
#pragma unroll
    for (int r = 0; r < 4; ++r) {
      if (j[r] >= 0) {
        const float w = wi[r] * dis[j[r]];
        bf16x8 v = *(const bf16x8*)&t[(size_t)j[r] * HH + c0];
#pragma unroll
        for (int k = 0; k < 8; ++k) acc[r][k] += w * (float)v[k];
      }
    }
  }

  float bv[8];
  if (f32io) {
    f32x4 b0 = *(const f32x4*)&((const float*)bias)[c0];
    f32x4 b1 = *(const f32x4*)&((const float*)bias)[c0 + 4];
#pragma unroll
    for (int k = 0; k < 4; ++k) { bv[k] = b0[k]; bv[4 + k] = b1[k]; }
  } else {
    bf16x8 bb = *(const bf16x8*)&((const u16*)bias)[c0];
#pragma unroll
    for (int k = 0; k < 8; ++k) bv[k] = (float)bb[k];
  }
#pragma unroll
  for (int r = 0; r < 4; ++r) {
    const int node = node0 + 2048 * r;
    float o[8];
#pragma unroll
    for (int k = 0; k < 8; ++k) {
      o[k] = acc[r][k] + bv[k];
      if (RELU) o[k] = fmaxf(o[k], 0.f);
    }
    if (FINAL && f32io) {
      float* O = (float*)y;
      f32x4 o0, o1;
#pragma unroll
      for (int k = 0; k < 4; ++k) { o0[k] = o[k]; o1[k] = o[4 + k]; }
      *(f32x4*)&O[(size_t)node * HH + c0] = o0;
      *(f32x4*)&O[(size_t)node * HH + c0 + 4] = o1;
    } else {
      bf16x8 ob;
#pragma unroll
      for (int k = 0; k < 8; ++k) ob[k] = (bf16)o[k];
      *(bf16x8*)&((u16*)y)[(size_t)node * HH + c0] = ob;
    }
  }
}

// prep work unit space U in [0,544): U<256 W2 tile; U<512 W3 tile; else dis
__device__ __forceinline__ void prep_unit(int U, const void* W2,
                                          const void* W3, u16* TW2, u16* TW3,
                                          const int* idx, int i64, float* dis,
                                          int f32in, u16* sm) {
  const int tid = threadIdx.x;
  if (U < 256) {
    transpose_tile(W2, TW2, U, f32in, sm);
  } else if (U < 512) {
    transpose_tile(W3, TW3, U - 256, f32in, sm);
  } else {
    const int i = (U - 512) * 256 + tid;
    int c = 1;
#pragma unroll
    for (int e = 0; e < MM; ++e) c += (idx[(i * MM + e) << i64] >= 0) ? 1 : 0;
    dis[i] = rsqrtf((float)c);
  }
}

// ---- single persistent kernel: whole pipeline, hierarchical grid syncs ----
// 512 blocks x 256 thr; 24KB LDS + launch_bounds(256,2) => 2 blocks/CU,
// all 512 co-resident. All cross-phase buffers are single-write (no reuse).
__global__ __launch_bounds__(256, 2) void mega_kernel(
    const u16* __restrict__ node, const u32* __restrict__ idxw,
    const void* __restrict__ Wemb, const void* __restrict__ bemb,
    const void* __restrict__ W1, const void* __restrict__ b1,
    const void* __restrict__ W2, const void* __restrict__ b2,
    const void* __restrict__ W3, const void* __restrict__ b3,
    float* __restrict__ dis, float* __restrict__ bvec, u16* __restrict__ TWc,
    u16* __restrict__ WembB, u16* __restrict__ TW1, u16* __restrict__ TW2,
    u16* __restrict__ TW3, u16* __restrict__ x1, u16* __restrict__ xO1,
    u16* __restrict__ x2, u16* __restrict__ xO2, u16* __restrict__ x3,
    u32* __restrict__ ctl, void* __restrict__ outp) {
  __shared__ __align__(16) u16 As[64 * 64];
  __shared__ __align__(16) u16 Bs[128 * 64];
  const int bid = blockIdx.x, tid = threadIdx.x;
  const int f32in = probe_f32(node);
  const int i64 = probe_i64(idxw);
  const int* idx = (const int*)idxw;

  // ---- P0: coherence startup + registration + Bx/nxcd broadcast
  BarSt bs{};
  bar_start(ctl, bs);

  // ---- P1: TW1 (0..255) + WembB (256..287) + prep head-start (288..511)
  if (bid < 256) {
    transpose_tile(W1, TW1, bid, f32in, As);
  } else if (bid < 288) {
    const size_t g = ((size_t)(bid - 256) * 256 + tid) * 8;  // 8 elems/thread
    bf16x8 o;
    if (f32in) {
      f32x4 a = *(const f32x4*)&((const float*)Wemb)[g];
      f32x4 bq = *(const f32x4*)&((const float*)Wemb)[g + 4];
#pragma unroll
      for (int t = 0; t < 4; ++t) { o[t] = (bf16)a[t]; o[4 + t] = (bf16)bq[t]; }
    } else {
      o = *(const bf16x8*)&((const u16*)Wemb)[g];
    }
    *(bf16x8*)&WembB[g] = o;
  } else {
    prep_unit(bid - 288, W2, W3, TW2, TW3, idx, i64, dis, f32in, As);
  }
  bar_phase(ctl, 1, bs);

  // ---- P2: TWc = TW1 @ Wemb^T (0..7) + bvec (8..9), in parallel with the
  //          remaining 320 prep units (blocks 10..329); 330+ idle
  if (bid < 8) {
    const u16* Bt = f32in ? WembB : (const u16*)Wemb;
    gemm_tile(TW1, HH, 0, Bt, nullptr, bid, 0, TWc, FN, As, Bs);
  } else if (bid < 10) {
    float* bembS = (float*)Bs;
    bembS[tid] = (float)cvt_elem(bemb, tid, f32in);
    bembS[256 + tid] = (float)cvt_elem(bemb, 256 + tid, f32in);
    __syncthreads();
    const int n = (bid - 8) * 256 + tid;  // 0..511
    float acc = 0.f;
#pragma unroll 8
    for (int m = 0; m < HH; m += 8) {
      bf16x8 w = *(const bf16x8*)&TW1[(size_t)n * HH + m];
#pragma unroll
      for (int jj = 0; jj < 8; ++jj) acc += bembS[m + jj] * (float)w[jj];
    }
    bvec[n] = acc;
  } else if (bid < 330) {
    prep_unit(224 + (bid - 10), W2, W3, TW2, TW3, idx, i64, dis, f32in, As);
  }
  bar_phase(ctl, 2, bs);

  // ---- P3: g1: x1 = node @ TWc^T + bvec  (K=128, A maybe fp32)
  gemm_tile(node, FN, f32in, TWc, bvec, bid & 127, bid >> 7, x1, HH, As, Bs);
  bar_phase(ctl, 3, bs);

  // ---- P4: agg1 + relu: xO1 = A~ x1
  agg_quad<true, false>(bid, x1, idx, i64, dis, b1, f32in, xO1);
  bar_phase(ctl, 4, bs);

  // ---- P5: gemm2: x2 = xO1 @ TW2^T
  gemm_tile(xO1, HH, 0, TW2, nullptr, bid & 127, bid >> 7, x2, HH, As, Bs);
  bar_phase(ctl, 5, bs);

  // ---- P6: agg2 + relu: xO2 = A~ x2
  agg_quad<true, false>(bid, x2, idx, i64, dis, b2, f32in, xO2);
  bar_phase(ctl, 6, bs);

  // ---- P7: gemm3: x3 = xO2 @ TW3^T
  gemm_tile(xO2, HH, 0, TW3, nullptr, bid & 127, bid >> 7, x3, HH, As, Bs);
  bar_phase(ctl, 7, bs);

  // ---- P8: agg3 (no relu, final dtype-matched store to d_out)
  agg_quad<false, true>(bid, x3, idx, i64, dis, b3, f32in, outp);
}

extern "C" void kernel_launch(void* const* d_in, const int* in_sizes, int n_in,
                              void* d_out, int out_size, void* d_ws, size_t ws_size,
                              hipStream_t stream) {
  const u16* node = (const u16*)d_in[0];
  const u32* idxw = (const u32*)d_in[1];
  const void* Wemb = d_in[2];
  const void* bemb = d_in[3];
  const void* W1 = d_in[4];
  const void* b1 = d_in[5];
  const void* W2 = d_in[6];
  const void* b2 = d_in[7];
  const void* W3 = d_in[8];
  const void* b3 = d_in[9];

  char* p = (char*)d_ws;
  float* dis = (float*)p;   p += NN * sizeof(float);
  float* bvec = (float*)p;  p += HH * sizeof(float);
  u16* TWc = (u16*)p;       p += (size_t)HH * FN * 2;
  u16* WembB = (u16*)p;     p += (size_t)FN * HH * 2;
  u16* TW1 = (u16*)p;       p += (size_t)HH * HH * 2;
  u16* TW2 = (u16*)p;       p += (size_t)HH * HH * 2;
  u16* TW3 = (u16*)p;       p += (size_t)HH * HH * 2;
  u16* x1 = (u16*)p;        p += (size_t)NN * HH * 2;  // single-write buffers
  u16* xO1 = (u16*)p;       p += (size_t)NN * HH * 2;
  u16* x2 = (u16*)p;        p += (size_t)NN * HH * 2;
  u16* xO2 = (u16*)p;       p += (size_t)NN * HH * 2;
  u16* x3 = (u16*)p;        p += (size_t)NN * HH * 2;
  u32* ctl = (u32*)p;       // barrier control block (zeroed per launch)

  hipMemsetAsync(ctl, 0, 4096, stream);
  mega_kernel<<<NBLK, 256, 0, stream>>>(node, idxw, Wemb, bemb, W1, b1, W2, b2,
                                        W3, b3, dis, bvec, TWc, WembB, TW1,
                                        TW2, TW3, x1, xO1, x2, xO2, x3, ctl,
                                        d_out);
}